// Round 1
// baseline (4260.432 us; speedup 1.0000x reference)
//
#include <hip/hip_runtime.h>
#include <math.h>

// ---------------------------------------------------------------------------
// Problem constants (from reference): B=8, T=1024, H=768, nh=12, Hs=64
// qkv layout in workspace: [B*T, 2304] row-major (q | k | v per row)
// att layout in workspace: [B*T, 768] row-major
// ---------------------------------------------------------------------------

#define TILE_M 64
#define TILE_N 64
#define TILE_K 16

// C[M,N] = A[M,K] @ B[K,N] + bias[N]; fp32, requires M%64==0, N%64==0, K%16==0
__global__ __launch_bounds__(256)
void gemm_bias_kernel(const float* __restrict__ A, const float* __restrict__ B,
                      const float* __restrict__ bias, float* __restrict__ C,
                      int M, int N, int K) {
    __shared__ float As[TILE_K][TILE_M + 4];  // padded: +4 keeps float4 16B align, breaks conflicts
    __shared__ float Bs[TILE_K][TILE_N + 4];

    const int tid = threadIdx.x;
    const int tx = tid & 15;   // n micro-tile index
    const int ty = tid >> 4;   // m micro-tile index
    const int m0 = blockIdx.x * TILE_M;
    const int n0 = blockIdx.y * TILE_N;

    float acc[4][4];
#pragma unroll
    for (int i = 0; i < 4; ++i)
#pragma unroll
        for (int j = 0; j < 4; ++j) acc[i][j] = 0.f;

    // staging assignments (256 threads, 64x16 A tile, 16x64 B tile, float4 each)
    const int a_row = tid >> 2;         // 0..63
    const int a_cg  = (tid & 3) * 4;    // k-offset 0,4,8,12
    const int b_row = tid >> 4;         // 0..15
    const int b_col = (tid & 15) * 4;   // 0..60

    for (int k0 = 0; k0 < K; k0 += TILE_K) {
        const float4 av = *(const float4*)(&A[(size_t)(m0 + a_row) * K + k0 + a_cg]);
        const float4 bv = *(const float4*)(&B[(size_t)(k0 + b_row) * N + n0 + b_col]);
        As[a_cg + 0][a_row] = av.x;
        As[a_cg + 1][a_row] = av.y;
        As[a_cg + 2][a_row] = av.z;
        As[a_cg + 3][a_row] = av.w;
        *(float4*)(&Bs[b_row][b_col]) = bv;
        __syncthreads();

#pragma unroll
        for (int kk = 0; kk < TILE_K; ++kk) {
            float a0 = As[kk][ty * 4 + 0];
            float a1 = As[kk][ty * 4 + 1];
            float a2 = As[kk][ty * 4 + 2];
            float a3 = As[kk][ty * 4 + 3];
            float b0 = Bs[kk][tx * 4 + 0];
            float b1 = Bs[kk][tx * 4 + 1];
            float b2 = Bs[kk][tx * 4 + 2];
            float b3 = Bs[kk][tx * 4 + 3];
            acc[0][0] += a0 * b0; acc[0][1] += a0 * b1; acc[0][2] += a0 * b2; acc[0][3] += a0 * b3;
            acc[1][0] += a1 * b0; acc[1][1] += a1 * b1; acc[1][2] += a1 * b2; acc[1][3] += a1 * b3;
            acc[2][0] += a2 * b0; acc[2][1] += a2 * b1; acc[2][2] += a2 * b2; acc[2][3] += a2 * b3;
            acc[3][0] += a3 * b0; acc[3][1] += a3 * b1; acc[3][2] += a3 * b2; acc[3][3] += a3 * b3;
        }
        __syncthreads();
    }

#pragma unroll
    for (int i = 0; i < 4; ++i) {
        const int m = m0 + ty * 4 + i;
#pragma unroll
        for (int j = 0; j < 4; ++j) {
            const int n = n0 + tx * 4 + j;
            C[(size_t)m * N + n] = acc[i][j] + bias[n];
        }
    }
}

// One wave per (b, h, query_i). Lane d holds q[d] and o[d] (Hs == 64 == wave).
// Online softmax over keys j <= i; coalesced 256B K/V row loads.
__global__ __launch_bounds__(256)
void attn_kernel(const float* __restrict__ qkv, float* __restrict__ out,
                 int Bn, int T, int nh) {
    const int H = 768, HS = 64, QKVW = 2304;
    const int wid  = blockIdx.x * 4 + (threadIdx.x >> 6);
    const int lane = threadIdx.x & 63;
    const int i  = wid & (T - 1);     // T = 1024 (pow2)
    const int bh = wid >> 10;         // / T
    const int h = bh % nh;
    const int b = bh / nh;

    const float* base = qkv + (size_t)b * T * QKVW + h * HS;
    const float q = base[(size_t)i * QKVW + lane];

    float m = -INFINITY, l = 0.f, o = 0.f;
    const float scale = 0.125f;  // 1/sqrt(64)

    for (int j = 0; j <= i; ++j) {
        const float* row = base + (size_t)j * QKVW;
        float kd = row[768 + lane];
        float p = q * kd;
#pragma unroll
        for (int off = 32; off >= 1; off >>= 1)
            p += __shfl_xor(p, off, 64);
        const float s  = p * scale;
        const float mn = fmaxf(m, s);
        const float alpha = __expf(m - mn);
        const float e     = __expf(s - mn);
        const float vd = row[1536 + lane];
        l = l * alpha + e;
        o = o * alpha + e * vd;
        m = mn;
    }
    out[((size_t)(b * T + i)) * H + h * HS + lane] = o / l;
}

extern "C" void kernel_launch(void* const* d_in, const int* in_sizes, int n_in,
                              void* d_out, int out_size, void* d_ws, size_t ws_size,
                              hipStream_t stream) {
    const float* x      = (const float*)d_in[0];
    const float* W_attn = (const float*)d_in[1];
    const float* b_attn = (const float*)d_in[2];
    const float* W_proj = (const float*)d_in[3];
    const float* b_proj = (const float*)d_in[4];
    float* out = (float*)d_out;

    const int Bn = 8, T = 1024, H = 768, nh = 12;
    const int M = Bn * T;  // 8192

    float* qkv = (float*)d_ws;                   // M * 2304 fp32 = 75.5 MB
    float* att = qkv + (size_t)M * 2304;         // M * 768  fp32 = 25.2 MB

    dim3 blk(256);

    // 1) qkv = x @ W_attn + b_attn   (8192 x 2304, K=768)
    dim3 g1(M / TILE_M, 2304 / TILE_N);
    gemm_bias_kernel<<<g1, blk, 0, stream>>>(x, W_attn, b_attn, qkv, M, 2304, H);

    // 2) causal MHA with online softmax  (one wave per (b,h,i))
    dim3 g2(Bn * nh * T / 4);
    attn_kernel<<<g2, blk, 0, stream>>>(qkv, att, Bn, T, nh);

    // 3) out = att @ W_proj + b_proj  (8192 x 768, K=768)
    dim3 g3(M / TILE_M, H / TILE_N);
    gemm_bias_kernel<<<g3, blk, 0, stream>>>(att, W_proj, b_proj, out, M, H, H);
}

// Round 2
// 980.225 us; speedup vs baseline: 4.3464x; 4.3464x over previous
//
#include <hip/hip_runtime.h>
#include <math.h>

// ---------------------------------------------------------------------------
// B=8, T=1024, H=768, nh=12, Hs=64
// ws: qkv [B*T, 2304] (q|k|v), att [B*T, 768]
// ---------------------------------------------------------------------------

#define TILE_M 64
#define TILE_N 64
#define TILE_K 16

// C[M,N] = A[M,K] @ B[K,N] + bias[N]; fp32 (already ~peak fp32 vector rate)
__global__ __launch_bounds__(256)
void gemm_bias_kernel(const float* __restrict__ A, const float* __restrict__ B,
                      const float* __restrict__ bias, float* __restrict__ C,
                      int M, int N, int K) {
    __shared__ float As[TILE_K][TILE_M + 4];
    __shared__ float Bs[TILE_K][TILE_N + 4];

    const int tid = threadIdx.x;
    const int tx = tid & 15;
    const int ty = tid >> 4;
    const int m0 = blockIdx.x * TILE_M;
    const int n0 = blockIdx.y * TILE_N;

    float acc[4][4];
#pragma unroll
    for (int i = 0; i < 4; ++i)
#pragma unroll
        for (int j = 0; j < 4; ++j) acc[i][j] = 0.f;

    const int a_row = tid >> 2;
    const int a_cg  = (tid & 3) * 4;
    const int b_row = tid >> 4;
    const int b_col = (tid & 15) * 4;

    for (int k0 = 0; k0 < K; k0 += TILE_K) {
        const float4 av = *(const float4*)(&A[(size_t)(m0 + a_row) * K + k0 + a_cg]);
        const float4 bv = *(const float4*)(&B[(size_t)(k0 + b_row) * N + n0 + b_col]);
        As[a_cg + 0][a_row] = av.x;
        As[a_cg + 1][a_row] = av.y;
        As[a_cg + 2][a_row] = av.z;
        As[a_cg + 3][a_row] = av.w;
        *(float4*)(&Bs[b_row][b_col]) = bv;
        __syncthreads();

#pragma unroll
        for (int kk = 0; kk < TILE_K; ++kk) {
            float a0 = As[kk][ty * 4 + 0];
            float a1 = As[kk][ty * 4 + 1];
            float a2 = As[kk][ty * 4 + 2];
            float a3 = As[kk][ty * 4 + 3];
            float b0 = Bs[kk][tx * 4 + 0];
            float b1 = Bs[kk][tx * 4 + 1];
            float b2 = Bs[kk][tx * 4 + 2];
            float b3 = Bs[kk][tx * 4 + 3];
            acc[0][0] += a0 * b0; acc[0][1] += a0 * b1; acc[0][2] += a0 * b2; acc[0][3] += a0 * b3;
            acc[1][0] += a1 * b0; acc[1][1] += a1 * b1; acc[1][2] += a1 * b2; acc[1][3] += a1 * b3;
            acc[2][0] += a2 * b0; acc[2][1] += a2 * b1; acc[2][2] += a2 * b2; acc[2][3] += a2 * b3;
            acc[3][0] += a3 * b0; acc[3][1] += a3 * b1; acc[3][2] += a3 * b2; acc[3][3] += a3 * b3;
        }
        __syncthreads();
    }

#pragma unroll
    for (int i = 0; i < 4; ++i) {
        const int m = m0 + ty * 4 + i;
#pragma unroll
        for (int j = 0; j < 4; ++j) {
            const int n = n0 + tx * 4 + j;
            C[(size_t)m * N + n] = acc[i][j] + bias[n];
        }
    }
}

// ---------------------------------------------------------------------------
// Flash attention: block = (b, h, 64-query tile). 256 threads (4 waves).
// Thread (ty=tid>>4, tx=tid&15) owns 4 queries (4*ty+i) x 4 keys/dims (4*tx+j).
// A q-row lives in 16 consecutive lanes of one wave -> shfl_xor 1/2/4/8 reduce.
// LDS (4 x 16 KB = 64 KB):
//   Qs[q][d]   plain (reads are row-broadcast)
//   Kt[d][k]   col-group swizzled by d>>2  (transpose write & GEMM read both ~conflict-free)
//   Vs[k][d]   col-group swizzled by k>>2
//   Ps[q][k]   plain (reads row-broadcast; write 8-way on 4 instrs/tile - negligible)
// ---------------------------------------------------------------------------
__global__ __launch_bounds__(256)
void flash_attn_kernel(const float* __restrict__ qkv, float* __restrict__ out) {
    const int T = 1024, H = 768, HS = 64, QKVW = 2304, NH = 12;

    __shared__ float Qs[64 * 64];
    __shared__ float Kt[64 * 64];
    __shared__ float Vs[64 * 64];
    __shared__ float Ps[64 * 64];

    const int tid = threadIdx.x;
    const int tx = tid & 15;
    const int ty = tid >> 4;

    const int qt = 15 - (blockIdx.x & 15);   // heavy (long) tiles dispatch first
    const int bh = blockIdx.x >> 4;
    const int h = bh % NH;
    const int b = bh / NH;
    const int q0 = qt * 64;

    const float* base = qkv + (size_t)b * T * QKVW + h * HS;

    // ---- load Q tile, pre-scaled by 1/sqrt(64) ----
#pragma unroll
    for (int r = 0; r < 4; ++r) {
        const int idx = r * 256 + tid;
        const int row = idx >> 4;
        const int col = (idx & 15) * 4;
        float4 v = *(const float4*)(base + (size_t)(q0 + row) * QKVW + col);
        v.x *= 0.125f; v.y *= 0.125f; v.z *= 0.125f; v.w *= 0.125f;
        *(float4*)(&Qs[row * 64 + col]) = v;
    }

    float o[4][4] = {};
    float mm[4], ll[4];
#pragma unroll
    for (int i = 0; i < 4; ++i) { mm[i] = -1e30f; ll[i] = 0.f; }

    for (int j0 = 0; j0 <= q0; j0 += 64) {
        __syncthreads();   // prev tile's PV done before overwriting Kt/Vs

        // ---- stage K (transposed, swizzled) and V (swizzled) ----
#pragma unroll
        for (int r = 0; r < 4; ++r) {
            const int idx = r * 256 + tid;
            const int krow = idx >> 4;         // key in tile (per-wave: 4 consecutive, 4-aligned)
            const int dcol = (idx & 15) * 4;   // dim group
            const float4 kv = *(const float4*)(base + (size_t)(j0 + krow) * QKVW + 768 + dcol);
            const float4 vv = *(const float4*)(base + (size_t)(j0 + krow) * QKVW + 1536 + dcol);
            // Kt: element (d=dcol+e, k=krow) -> Kt[d*64 + ((k>>2 ^ d>>2)<<2 | (k&3))]
            const int kq = krow >> 2, kr = krow & 3, dq = dcol >> 2;
            Kt[(dcol + 0) * 64 + (((kq ^ dq) << 2) | kr)] = kv.x;
            Kt[(dcol + 1) * 64 + (((kq ^ dq) << 2) | kr)] = kv.y;
            Kt[(dcol + 2) * 64 + (((kq ^ dq) << 2) | kr)] = kv.z;
            Kt[(dcol + 3) * 64 + (((kq ^ dq) << 2) | kr)] = kv.w;
            // Vs: element (k=krow, d) -> Vs[k*64 + ((d>>2 ^ k>>2)<<2 | (d&3))]; contiguous in d
            *(float4*)(&Vs[krow * 64 + (((dq ^ kq) << 2))]) = vv;
        }
        __syncthreads();

        // ---- S = Q*K^T (4x4 micro-tile per thread) ----
        float s[4][4] = {};
#pragma unroll 4
        for (int d = 0; d < 64; d += 4) {
            float4 qv[4], kv[4];
            const int kg = (tx ^ (d >> 2)) << 2;
#pragma unroll
            for (int i = 0; i < 4; ++i) qv[i] = *(const float4*)(&Qs[(ty * 4 + i) * 64 + d]);
#pragma unroll
            for (int e = 0; e < 4; ++e) kv[e] = *(const float4*)(&Kt[(d + e) * 64 + kg]);
#pragma unroll
            for (int i = 0; i < 4; ++i) {
                const float* qp = (const float*)&qv[i];
#pragma unroll
                for (int e = 0; e < 4; ++e) {
                    const float a = qp[e];
                    s[i][0] += a * kv[e].x;
                    s[i][1] += a * kv[e].y;
                    s[i][2] += a * kv[e].z;
                    s[i][3] += a * kv[e].w;
                }
            }
        }

        // ---- causal mask (only diagonal tile has masked entries) ----
        if (j0 == q0) {
            const int qg = ty * 4, kg = tx * 4;
#pragma unroll
            for (int i = 0; i < 4; ++i)
#pragma unroll
                for (int j = 0; j < 4; ++j)
                    if (kg + j > qg + i) s[i][j] = -1e30f;
        }

        // ---- online softmax per q-row (16-lane groups) + write P ----
#pragma unroll
        for (int i = 0; i < 4; ++i) {
            float rm = fmaxf(fmaxf(s[i][0], s[i][1]), fmaxf(s[i][2], s[i][3]));
#pragma unroll
            for (int off = 8; off >= 1; off >>= 1)
                rm = fmaxf(rm, __shfl_xor(rm, off, 64));
            const float mn = fmaxf(mm[i], rm);
            const float p0 = __expf(s[i][0] - mn);
            const float p1 = __expf(s[i][1] - mn);
            const float p2 = __expf(s[i][2] - mn);
            const float p3 = __expf(s[i][3] - mn);
            float rs = p0 + p1 + p2 + p3;
#pragma unroll
            for (int off = 8; off >= 1; off >>= 1)
                rs += __shfl_xor(rs, off, 64);
            const float alpha = __expf(mm[i] - mn);
            mm[i] = mn;
            ll[i] = ll[i] * alpha + rs;
            o[i][0] *= alpha; o[i][1] *= alpha; o[i][2] *= alpha; o[i][3] *= alpha;
            float4 pv = {p0, p1, p2, p3};
            *(float4*)(&Ps[(ty * 4 + i) * 64 + tx * 4]) = pv;
        }
        __syncthreads();

        // ---- O += P * V ----
#pragma unroll 4
        for (int k = 0; k < 64; k += 4) {
            float4 pv[4], vv[4];
            const int vg = (tx ^ (k >> 2)) << 2;
#pragma unroll
            for (int i = 0; i < 4; ++i) pv[i] = *(const float4*)(&Ps[(ty * 4 + i) * 64 + k]);
#pragma unroll
            for (int e = 0; e < 4; ++e) vv[e] = *(const float4*)(&Vs[(k + e) * 64 + vg]);
#pragma unroll
            for (int i = 0; i < 4; ++i) {
                const float* pp = (const float*)&pv[i];
#pragma unroll
                for (int e = 0; e < 4; ++e) {
                    const float a = pp[e];
                    o[i][0] += a * vv[e].x;
                    o[i][1] += a * vv[e].y;
                    o[i][2] += a * vv[e].z;
                    o[i][3] += a * vv[e].w;
                }
            }
        }
    }

    // ---- finalize: out[b*T+q][h*64+d] = o/l ----
#pragma unroll
    for (int i = 0; i < 4; ++i) {
        const float inv = 1.0f / ll[i];
        float4 r;
        r.x = o[i][0] * inv; r.y = o[i][1] * inv; r.z = o[i][2] * inv; r.w = o[i][3] * inv;
        const int q = q0 + ty * 4 + i;
        *(float4*)(out + ((size_t)(b * T + q)) * H + h * HS + tx * 4) = r;
    }
}

extern "C" void kernel_launch(void* const* d_in, const int* in_sizes, int n_in,
                              void* d_out, int out_size, void* d_ws, size_t ws_size,
                              hipStream_t stream) {
    const float* x      = (const float*)d_in[0];
    const float* W_attn = (const float*)d_in[1];
    const float* b_attn = (const float*)d_in[2];
    const float* W_proj = (const float*)d_in[3];
    const float* b_proj = (const float*)d_in[4];
    float* out = (float*)d_out;

    const int Bn = 8, T = 1024, H = 768, nh = 12;
    const int M = Bn * T;  // 8192

    float* qkv = (float*)d_ws;                   // M * 2304 fp32
    float* att = qkv + (size_t)M * 2304;         // M * 768  fp32

    dim3 blk(256);

    // 1) qkv = x @ W_attn + b_attn
    dim3 g1(M / TILE_M, 2304 / TILE_N);
    gemm_bias_kernel<<<g1, blk, 0, stream>>>(x, W_attn, b_attn, qkv, M, 2304, H);

    // 2) flash attention
    dim3 g2(Bn * nh * (T / 64));  // 1536 blocks
    flash_attn_kernel<<<g2, blk, 0, stream>>>(qkv, att);

    // 3) out = att @ W_proj + b_proj
    dim3 g3(M / TILE_M, H / TILE_N);
    gemm_bias_kernel<<<g3, blk, 0, stream>>>(att, W_proj, b_proj, out, M, H, H);
}

// Round 3
// 246.811 us; speedup vs baseline: 17.2619x; 3.9716x over previous
//
#include <hip/hip_runtime.h>
#include <math.h>

// ---------------------------------------------------------------------------
// B=8, T=1024, H=768, nh=12, Hs=64.  All matmuls in bf16 MFMA, fp32 accum.
// ws: xb[8192*768]bf16 | Wta[2304*768]bf16 (n-major) | Wtp[768*768]bf16 (n-major)
//     qkvb[8192*2304]bf16 | attb[8192*768]bf16
// ---------------------------------------------------------------------------

typedef __attribute__((ext_vector_type(4))) float  f32x4;
typedef __attribute__((ext_vector_type(8))) short  bf16x8;
typedef __attribute__((ext_vector_type(4))) short  bf16x4;
typedef __attribute__((ext_vector_type(4))) unsigned int u32x4;

__device__ __forceinline__ unsigned short f2bf(float f) {
    union { float f; unsigned u; } v; v.f = f;
    unsigned r = (v.u + 0x7FFFu + ((v.u >> 16) & 1u)) >> 16;   // RNE
    return (unsigned short)r;
}

// ---- x (fp32) -> bf16, 4 elems/thread -------------------------------------
__global__ __launch_bounds__(256)
void cvt_f32_bf16(const float* __restrict__ in, unsigned short* __restrict__ out) {
    const int i = blockIdx.x * 256 + threadIdx.x;
    const float4 v = ((const float4*)in)[i];
    ushort4 o;
    o.x = f2bf(v.x); o.y = f2bf(v.y); o.z = f2bf(v.z); o.w = f2bf(v.w);
    ((ushort4*)out)[i] = o;
}

// ---- W fp32 [K][N] -> Wt bf16 [N][K] (64x64 LDS tile transpose) -----------
__global__ __launch_bounds__(256)
void transpose_w(const float* __restrict__ W, unsigned short* __restrict__ Wt,
                 int K, int N) {
    __shared__ float Ts[64][65];
    const int k0 = blockIdx.x * 64, n0 = blockIdx.y * 64;
    const int t = threadIdx.x;
    const int r = t >> 4, cg = (t & 15) * 4;
#pragma unroll
    for (int p = 0; p < 4; ++p) {
        const float4 v = *(const float4*)(&W[(size_t)(k0 + r + p * 16) * N + n0 + cg]);
        Ts[r + p * 16][cg + 0] = v.x;
        Ts[r + p * 16][cg + 1] = v.y;
        Ts[r + p * 16][cg + 2] = v.z;
        Ts[r + p * 16][cg + 3] = v.w;
    }
    __syncthreads();
#pragma unroll
    for (int p = 0; p < 4; ++p) {
        const int n = n0 + r + p * 16;
        ushort4 o;
        o.x = f2bf(Ts[cg + 0][r + p * 16]);
        o.y = f2bf(Ts[cg + 1][r + p * 16]);
        o.z = f2bf(Ts[cg + 2][r + p * 16]);
        o.w = f2bf(Ts[cg + 3][r + p * 16]);
        *(ushort4*)(&Wt[(size_t)n * K + k0 + cg]) = o;
    }
}

// ---------------------------------------------------------------------------
// bf16 MFMA GEMM: C[M,N] = A[M,K] @ B[K,N] + bias, with B given TRANSPOSED
// (Bt[N][K]).  128x128 tile, 256 threads = 4 waves (2x2), each wave 64x64 =
// 4x4 tiles of mfma_f32_16x16x32_bf16.  BK=32.  LDS rows padded to 40 bf16
// (80 B = 20 dwords, odd*4 -> 2-way max on b128 frag reads).
// ---------------------------------------------------------------------------
__global__ __launch_bounds__(256)
void gemm_bf16(const unsigned short* __restrict__ A, const unsigned short* __restrict__ Bt,
               const float* __restrict__ bias, void* __restrict__ Cout,
               int M, int N, int K, int out_bf16) {
    __shared__ unsigned short As[128 * 40];
    __shared__ unsigned short Bs[128 * 40];

    const int t = threadIdx.x;
    const int L = t & 63, w = t >> 6;
    const int l15 = L & 15, quad = L >> 4;
    const int wy = w & 1, wx = w >> 1;
    const int m0 = blockIdx.x * 128, n0 = blockIdx.y * 128;

    const int srow = t >> 1, shalf = t & 1;
    const unsigned short* ag = A + (size_t)(m0 + srow) * K + shalf * 16;
    const unsigned short* bg = Bt + (size_t)(n0 + srow) * K + shalf * 16;
    unsigned short* asw = As + srow * 40 + shalf * 16;
    unsigned short* bsw = Bs + srow * 40 + shalf * 16;

    f32x4 acc[4][4];
#pragma unroll
    for (int mt = 0; mt < 4; ++mt)
#pragma unroll
        for (int nt = 0; nt < 4; ++nt) acc[mt][nt] = (f32x4){0.f, 0.f, 0.f, 0.f};

    for (int k0 = 0; k0 < K; k0 += 32) {
        const u32x4 a0 = *(const u32x4*)(ag + k0);
        const u32x4 a1 = *(const u32x4*)(ag + k0 + 8);
        const u32x4 b0 = *(const u32x4*)(bg + k0);
        const u32x4 b1 = *(const u32x4*)(bg + k0 + 8);
        *(u32x4*)asw = a0; *(u32x4*)(asw + 8) = a1;
        *(u32x4*)bsw = b0; *(u32x4*)(bsw + 8) = b1;
        __syncthreads();

        bf16x8 af[4], bf[4];
#pragma unroll
        for (int mt = 0; mt < 4; ++mt)
            af[mt] = *(const bf16x8*)(As + (wy * 64 + mt * 16 + l15) * 40 + quad * 8);
#pragma unroll
        for (int nt = 0; nt < 4; ++nt)
            bf[nt] = *(const bf16x8*)(Bs + (wx * 64 + nt * 16 + l15) * 40 + quad * 8);
#pragma unroll
        for (int mt = 0; mt < 4; ++mt)
#pragma unroll
            for (int nt = 0; nt < 4; ++nt)
                acc[mt][nt] = __builtin_amdgcn_mfma_f32_16x16x32_bf16(af[mt], bf[nt], acc[mt][nt], 0, 0, 0);
        __syncthreads();
    }

    float bv[4];
#pragma unroll
    for (int nt = 0; nt < 4; ++nt) bv[nt] = bias[n0 + wx * 64 + nt * 16 + l15];
#pragma unroll
    for (int mt = 0; mt < 4; ++mt) {
        const int mrow = m0 + wy * 64 + mt * 16 + quad * 4;
#pragma unroll
        for (int r = 0; r < 4; ++r) {
            const int m = mrow + r;
            if (out_bf16) {
                unsigned short* C = (unsigned short*)Cout;
#pragma unroll
                for (int nt = 0; nt < 4; ++nt)
                    C[(size_t)m * N + n0 + wx * 64 + nt * 16 + l15] = f2bf(acc[mt][nt][r] + bv[nt]);
            } else {
                float* C = (float*)Cout;
#pragma unroll
                for (int nt = 0; nt < 4; ++nt)
                    C[(size_t)m * N + n0 + wx * 64 + nt * 16 + l15] = acc[mt][nt][r] + bv[nt];
            }
        }
    }
}

// ---------------------------------------------------------------------------
// MFMA flash attention.  Block = (b,h,64-query tile), 256 thr = 4 waves,
// wave w owns queries q0+16w..+15 (query = col = lane&15).
// S^T = K.Q^T via mfma_16x16x32 (A=K rows, B=Q^T).  C-layout of S^T
// (row=key=4*quad+r, col=query=lane&15) IS the B-operand layout of P^T for
// mfma_16x16x16bf16_1k, so PV = V^T.P^T needs no LDS round-trip for P.
// V staged transposed (Vt[dim][key], stride 72) via 4x4 register transpose.
// Softmax per query col: local max/sum over 16 regs + shfl_xor 16,32.
// Scale 1/8 folded into exp2 constant SM = 0.125*log2(e).
// ---------------------------------------------------------------------------
__global__ __launch_bounds__(256)
void attn_mfma(const unsigned short* __restrict__ qkv, unsigned short* __restrict__ attb) {
    const int T = 1024, QKVW = 2304, NH = 12, H = 768;
    __shared__ unsigned short Ks[64 * 72];   // also Q staging, also O staging
    __shared__ unsigned short Vt[64 * 72];

    const int t = threadIdx.x;
    const int L = t & 63, w = t >> 6;
    const int l15 = L & 15, quad = L >> 4;
    const int qt = 15 - (blockIdx.x & 15);   // long tiles first
    const int bh = blockIdx.x >> 4;
    const int h = bh % NH, b = bh / NH;
    const int q0 = qt * 64;

    const unsigned short* base = qkv + (size_t)b * T * QKVW + h * 64;

    // ---- stage Q, load Q^T B-frags into regs ----
    {
        const unsigned short* src = base + (size_t)(q0 + (t & 63)) * QKVW + (t >> 6) * 16;
        const u32x4 v0 = *(const u32x4*)src;
        const u32x4 v1 = *(const u32x4*)(src + 8);
        unsigned short* dst = Ks + (t & 63) * 72 + (t >> 6) * 16;
        *(u32x4*)dst = v0; *(u32x4*)(dst + 8) = v1;
    }
    __syncthreads();
    bf16x8 qf[2];
    qf[0] = *(const bf16x8*)(Ks + (16 * w + l15) * 72 + quad * 8);
    qf[1] = *(const bf16x8*)(Ks + (16 * w + l15) * 72 + 32 + quad * 8);

    f32x4 ot[4];
#pragma unroll
    for (int dt = 0; dt < 4; ++dt) ot[dt] = (f32x4){0.f, 0.f, 0.f, 0.f};
    float mrun = -1e30f, lsum = 0.f;
    const float SM = 0.18033688f;   // 0.125 * log2(e)

    for (int j0 = 0; j0 <= q0; j0 += 64) {
        __syncthreads();   // frag reads / prev tile done before restaging
        {   // stage K rows
            const unsigned short* src = base + (size_t)(j0 + (t & 63)) * QKVW + 768 + (t >> 6) * 16;
            const u32x4 v0 = *(const u32x4*)src;
            const u32x4 v1 = *(const u32x4*)(src + 8);
            unsigned short* dst = Ks + (t & 63) * 72 + (t >> 6) * 16;
            *(u32x4*)dst = v0; *(u32x4*)(dst + 8) = v1;
        }
        {   // stage V^T: 4x4 block transpose in regs
            const int k4 = (t & 15) * 4, d4 = (t >> 4) * 4;
            const unsigned short* vb = base + 1536 + d4;
            const ushort4 r0 = *(const ushort4*)(vb + (size_t)(j0 + k4 + 0) * QKVW);
            const ushort4 r1 = *(const ushort4*)(vb + (size_t)(j0 + k4 + 1) * QKVW);
            const ushort4 r2 = *(const ushort4*)(vb + (size_t)(j0 + k4 + 2) * QKVW);
            const ushort4 r3 = *(const ushort4*)(vb + (size_t)(j0 + k4 + 3) * QKVW);
            ushort4 c0, c1, c2, c3;
            c0.x = r0.x; c0.y = r1.x; c0.z = r2.x; c0.w = r3.x;
            c1.x = r0.y; c1.y = r1.y; c1.z = r2.y; c1.w = r3.y;
            c2.x = r0.z; c2.y = r1.z; c2.z = r2.z; c2.w = r3.z;
            c3.x = r0.w; c3.y = r1.w; c3.z = r2.w; c3.w = r3.w;
            *(ushort4*)(Vt + (size_t)(d4 + 0) * 72 + k4) = c0;
            *(ushort4*)(Vt + (size_t)(d4 + 1) * 72 + k4) = c1;
            *(ushort4*)(Vt + (size_t)(d4 + 2) * 72 + k4) = c2;
            *(ushort4*)(Vt + (size_t)(d4 + 3) * 72 + k4) = c3;
        }
        __syncthreads();

        // ---- S^T = K.Q^T ----
        f32x4 st[4];
#pragma unroll
        for (int mt = 0; mt < 4; ++mt) {
            st[mt] = (f32x4){0.f, 0.f, 0.f, 0.f};
            const bf16x8 kf0 = *(const bf16x8*)(Ks + (16 * mt + l15) * 72 + quad * 8);
            const bf16x8 kf1 = *(const bf16x8*)(Ks + (16 * mt + l15) * 72 + 32 + quad * 8);
            st[mt] = __builtin_amdgcn_mfma_f32_16x16x32_bf16(kf0, qf[0], st[mt], 0, 0, 0);
            st[mt] = __builtin_amdgcn_mfma_f32_16x16x32_bf16(kf1, qf[1], st[mt], 0, 0, 0);
        }

        // ---- causal mask (diagonal tile only) ----
        if (j0 == q0) {
            const int qin = 16 * w + l15;
#pragma unroll
            for (int mt = 0; mt < 4; ++mt)
#pragma unroll
                for (int r = 0; r < 4; ++r)
                    if (16 * mt + 4 * quad + r > qin) st[mt][r] = -1e30f;
        }

        // ---- online softmax (per query col) ----
        float nm = st[0][0];
#pragma unroll
        for (int mt = 0; mt < 4; ++mt)
#pragma unroll
            for (int r = 0; r < 4; ++r) nm = fmaxf(nm, st[mt][r]);
        nm = fmaxf(nm, __shfl_xor(nm, 16, 64));
        nm = fmaxf(nm, __shfl_xor(nm, 32, 64));
        const float mnew = fmaxf(mrun, nm);
        const float alpha = __builtin_amdgcn_exp2f((mrun - mnew) * SM);
        float ps[4][4];
        float rs = 0.f;
#pragma unroll
        for (int mt = 0; mt < 4; ++mt)
#pragma unroll
            for (int r = 0; r < 4; ++r) {
                const float p = __builtin_amdgcn_exp2f((st[mt][r] - mnew) * SM);
                ps[mt][r] = p; rs += p;
            }
        rs += __shfl_xor(rs, 16, 64);
        rs += __shfl_xor(rs, 32, 64);
        lsum = lsum * alpha + rs;
        mrun = mnew;
#pragma unroll
        for (int dt = 0; dt < 4; ++dt) {
            ot[dt][0] *= alpha; ot[dt][1] *= alpha; ot[dt][2] *= alpha; ot[dt][3] *= alpha;
        }

        // ---- P^T regs -> bf16 B-frags ----
        bf16x4 pf[4];
#pragma unroll
        for (int c = 0; c < 4; ++c) {
            bf16x4 p;
            p[0] = (short)f2bf(ps[c][0]);
            p[1] = (short)f2bf(ps[c][1]);
            p[2] = (short)f2bf(ps[c][2]);
            p[3] = (short)f2bf(ps[c][3]);
            pf[c] = p;
        }

        // ---- O^T += V^T . P^T ----
#pragma unroll
        for (int c = 0; c < 4; ++c)
#pragma unroll
            for (int dt = 0; dt < 4; ++dt) {
                const bf16x4 vf = *(const bf16x4*)(Vt + (size_t)(16 * dt + l15) * 72 + 16 * c + 4 * quad);
                ot[dt] = __builtin_amdgcn_mfma_f32_16x16x16bf16_1k(vf, pf[c], ot[dt], 0, 0, 0);
            }
    }

    // ---- epilogue: O^T/l -> LDS transpose -> coalesced bf16 stores ----
    __syncthreads();
    const float inv = 1.0f / lsum;
#pragma unroll
    for (int dt = 0; dt < 4; ++dt)
#pragma unroll
        for (int r = 0; r < 4; ++r)
            Ks[(16 * w + l15) * 72 + 16 * dt + 4 * quad + r] = f2bf(ot[dt][r] * inv);
    __syncthreads();
    {
        const int row = t & 63, half = t >> 6;
        const u32x4 v0 = *(const u32x4*)(Ks + row * 72 + half * 16);
        const u32x4 v1 = *(const u32x4*)(Ks + row * 72 + half * 16 + 8);
        unsigned short* dst = attb + (size_t)(b * T + q0 + row) * H + h * 64 + half * 16;
        *(u32x4*)dst = v0; *(u32x4*)(dst + 8) = v1;
    }
}

extern "C" void kernel_launch(void* const* d_in, const int* in_sizes, int n_in,
                              void* d_out, int out_size, void* d_ws, size_t ws_size,
                              hipStream_t stream) {
    const float* x      = (const float*)d_in[0];
    const float* W_attn = (const float*)d_in[1];
    const float* b_attn = (const float*)d_in[2];
    const float* W_proj = (const float*)d_in[3];
    const float* b_proj = (const float*)d_in[4];
    float* out = (float*)d_out;

    const int Bn = 8, T = 1024, H = 768, NH = 12;
    const int M = Bn * T;            // 8192
    const int N1 = 3 * H;            // 2304

    // workspace layout (bf16 = unsigned short)
    unsigned short* xb   = (unsigned short*)d_ws;                 // M*H
    unsigned short* Wta  = xb + (size_t)M * H;                    // N1*H (n-major)
    unsigned short* Wtp  = Wta + (size_t)N1 * H;                  // H*H  (n-major)
    unsigned short* qkvb = Wtp + (size_t)H * H;                   // M*N1
    unsigned short* attb = qkvb + (size_t)M * N1;                 // M*H

    dim3 blk(256);

    // 0) conversions
    cvt_f32_bf16<<<dim3((M * H) / 1024), blk, 0, stream>>>(x, xb);
    transpose_w<<<dim3(H / 64, N1 / 64), blk, 0, stream>>>(W_attn, Wta, H, N1);
    transpose_w<<<dim3(H / 64, H / 64), blk, 0, stream>>>(W_proj, Wtp, H, H);

    // 1) qkv = x @ W_attn + b_attn  (bf16 out)
    gemm_bf16<<<dim3(M / 128, N1 / 128), blk, 0, stream>>>(xb, Wta, b_attn, qkvb, M, N1, H, 1);

    // 2) flash attention (bf16 MFMA)
    attn_mfma<<<dim3(Bn * NH * (T / 64)), blk, 0, stream>>>(qkvb, attb);

    // 3) out = att @ W_proj + b_proj  (fp32 out)
    gemm_bf16<<<dim3(M / 128, H / 128), blk, 0, stream>>>(attb, Wtp, b_proj, out, M, H, H, 0);
}

// Round 4
// 205.269 us; speedup vs baseline: 20.7553x; 1.2024x over previous
//
#include <hip/hip_runtime.h>
#include <math.h>

// ---------------------------------------------------------------------------
// B=8, T=1024, H=768, nh=12, Hs=64.  All matmuls bf16 MFMA, fp32 accum.
// ws: xb[8192*768]bf16 | Wta[2304*768]bf16 (n-major) | Wtp[768*768]bf16 (n-major)
//     qkvb[8192*2304]bf16 | attb[8192*768]bf16
// ---------------------------------------------------------------------------

typedef __attribute__((ext_vector_type(4))) float  f32x4;
typedef __attribute__((ext_vector_type(8))) short  bf16x8;
typedef __attribute__((ext_vector_type(4))) short  bf16x4;
typedef __attribute__((ext_vector_type(4))) unsigned int u32x4;

__device__ __forceinline__ unsigned short f2bf(float f) {
    union { float f; unsigned u; } v; v.f = f;
    unsigned r = (v.u + 0x7FFFu + ((v.u >> 16) & 1u)) >> 16;   // RNE
    return (unsigned short)r;
}

// async global->LDS, 16B per lane.  LDS side is wave-uniform-base + lane*16;
// per-thread l must be consistent with that (it is, by construction below).
__device__ __forceinline__ void glds16(const unsigned short* g, unsigned short* l) {
    __builtin_amdgcn_global_load_lds((const __attribute__((address_space(1))) void*)g,
                                     (__attribute__((address_space(3))) void*)l, 16, 0, 0);
}

// ---- x (fp32) -> bf16, 4 elems/thread -------------------------------------
__global__ __launch_bounds__(256)
void cvt_f32_bf16(const float* __restrict__ in, unsigned short* __restrict__ out) {
    const int i = blockIdx.x * 256 + threadIdx.x;
    const float4 v = ((const float4*)in)[i];
    ushort4 o;
    o.x = f2bf(v.x); o.y = f2bf(v.y); o.z = f2bf(v.z); o.w = f2bf(v.w);
    ((ushort4*)out)[i] = o;
}

// ---- W fp32 [K][N] -> Wt bf16 [N][K] (64x64 LDS tile transpose) -----------
__global__ __launch_bounds__(256)
void transpose_w(const float* __restrict__ W, unsigned short* __restrict__ Wt,
                 int K, int N) {
    __shared__ float Ts[64][65];
    const int k0 = blockIdx.x * 64, n0 = blockIdx.y * 64;
    const int t = threadIdx.x;
    const int r = t >> 4, cg = (t & 15) * 4;
#pragma unroll
    for (int p = 0; p < 4; ++p) {
        const float4 v = *(const float4*)(&W[(size_t)(k0 + r + p * 16) * N + n0 + cg]);
        Ts[r + p * 16][cg + 0] = v.x;
        Ts[r + p * 16][cg + 1] = v.y;
        Ts[r + p * 16][cg + 2] = v.z;
        Ts[r + p * 16][cg + 3] = v.w;
    }
    __syncthreads();
#pragma unroll
    for (int p = 0; p < 4; ++p) {
        const int n = n0 + r + p * 16;
        ushort4 o;
        o.x = f2bf(Ts[cg + 0][r + p * 16]);
        o.y = f2bf(Ts[cg + 1][r + p * 16]);
        o.z = f2bf(Ts[cg + 2][r + p * 16]);
        o.w = f2bf(Ts[cg + 3][r + p * 16]);
        *(ushort4*)(&Wt[(size_t)n * K + k0 + cg]) = o;
    }
}

// ---------------------------------------------------------------------------
// m97-style bf16 MFMA GEMM: C[M,N] = A[M,K] @ Bt[N,K]^T + bias.
// 128x128 tile, 4 waves (2x2), 16x16x32 mfma, BK=32, unpadded 64B LDS rows,
// global_load_lds width 16 staging (4 issues / K-step).
// ---------------------------------------------------------------------------
__global__ __launch_bounds__(256)
void gemm_bf16(const unsigned short* __restrict__ A, const unsigned short* __restrict__ Bt,
               const float* __restrict__ bias, void* __restrict__ Cout,
               int M, int N, int K, int out_bf16) {
    __shared__ unsigned short As[128 * 32];
    __shared__ unsigned short Bs[128 * 32];

    const int t = threadIdx.x;
    const int L = t & 63, w = t >> 6;
    const int l15 = L & 15, quad = L >> 4;
    const int wy = w & 1, wx = w >> 1;
    const int m0 = blockIdx.x * 128, n0 = blockIdx.y * 128;

    const int srow = t >> 2, koff = (t & 3) * 8;
    const unsigned short* ag = A + (size_t)(m0 + srow) * K + koff;
    const unsigned short* bg = Bt + (size_t)(n0 + srow) * K + koff;
    unsigned short* as0 = As + srow * 32 + koff;
    unsigned short* bs0 = Bs + srow * 32 + koff;
    const size_t gstep = (size_t)64 * K;

    f32x4 acc[4][4];
#pragma unroll
    for (int mt = 0; mt < 4; ++mt)
#pragma unroll
        for (int nt = 0; nt < 4; ++nt) acc[mt][nt] = (f32x4){0.f, 0.f, 0.f, 0.f};

    for (int k0 = 0; k0 < K; k0 += 32) {
        glds16(ag + k0,         as0);
        glds16(ag + gstep + k0, as0 + 64 * 32);
        glds16(bg + k0,         bs0);
        glds16(bg + gstep + k0, bs0 + 64 * 32);
        __syncthreads();

        bf16x8 af[4], bfr[4];
#pragma unroll
        for (int mt = 0; mt < 4; ++mt)
            af[mt] = *(const bf16x8*)(As + (wy * 64 + mt * 16 + l15) * 32 + quad * 8);
#pragma unroll
        for (int nt = 0; nt < 4; ++nt)
            bfr[nt] = *(const bf16x8*)(Bs + (wx * 64 + nt * 16 + l15) * 32 + quad * 8);
#pragma unroll
        for (int mt = 0; mt < 4; ++mt)
#pragma unroll
            for (int nt = 0; nt < 4; ++nt)
                acc[mt][nt] = __builtin_amdgcn_mfma_f32_16x16x32_bf16(af[mt], bfr[nt], acc[mt][nt], 0, 0, 0);
        __syncthreads();
    }

    float bv[4];
#pragma unroll
    for (int nt = 0; nt < 4; ++nt) bv[nt] = bias[n0 + wx * 64 + nt * 16 + l15];
#pragma unroll
    for (int mt = 0; mt < 4; ++mt) {
        const int mrow = m0 + wy * 64 + mt * 16 + quad * 4;
#pragma unroll
        for (int r = 0; r < 4; ++r) {
            const int m = mrow + r;
            if (out_bf16) {
                unsigned short* C = (unsigned short*)Cout;
#pragma unroll
                for (int nt = 0; nt < 4; ++nt)
                    C[(size_t)m * N + n0 + wx * 64 + nt * 16 + l15] = f2bf(acc[mt][nt][r] + bv[nt]);
            } else {
                float* C = (float*)Cout;
#pragma unroll
                for (int nt = 0; nt < 4; ++nt)
                    C[(size_t)m * N + n0 + wx * 64 + nt * 16 + l15] = acc[mt][nt][r] + bv[nt];
            }
        }
    }
}

// ---------------------------------------------------------------------------
// MFMA flash attention, load-balanced: block p handles q-tiles (15-p, p)
// -> every block does exactly 17 j-tiles.  Grid = 96 heads * 8 = 768 blocks.
// K/Q staged via global_load_lds into XOR-swizzled Ks[64][64]:
//   logical 16B chunk lc of row r lives at physical chunk lc ^ (r&7)
//   (write side: lane picks matching global address; read side: <=2-way).
// S^T = K.Q^T (16x16x32); S^T C-regs ARE the B-frags of 16x16x16bf16_1k for
// PV = V^T.P^T (no LDS round-trip for P).  V^T staged by register transpose.
// ---------------------------------------------------------------------------
__global__ __launch_bounds__(256)
void attn_mfma(const unsigned short* __restrict__ qkv, unsigned short* __restrict__ attb) {
    const int T = 1024, QKVW = 2304, NH = 12, H = 768;
    __shared__ unsigned short Ks[64 * 64];   // swizzled; Q then K tiles
    __shared__ unsigned short Vt[64 * 72];   // V^T (stride 72); also O staging

    const int t = threadIdx.x;
    const int L = t & 63, w = t >> 6;
    const int l15 = L & 15, quad = L >> 4;
    const int pair = blockIdx.x & 7;
    const int bh = blockIdx.x >> 3;
    const int h = bh % NH, b = bh / NH;

    const unsigned short* base = qkv + (size_t)b * T * QKVW + h * 64;

    // swizzled staging: round s covers 16B chunks g = s*256 + t of the tile
    const int g0 = t,        r0 = g0 >> 3, lc0 = (g0 & 7) ^ (r0 & 7);
    const int g1 = 256 + t,  r1 = g1 >> 3, lc1 = (g1 & 7) ^ (r1 & 7);
    const float SM = 0.18033688f;   // 0.125 * log2(e)

    for (int sub = 0; sub < 2; ++sub) {
        const int qt = sub ? pair : 15 - pair;
        const int q0 = qt * 64;

        __syncthreads();   // prior sub fully done with Ks/Vt
        glds16(base + (size_t)(q0 + r0) * QKVW + lc0 * 8, Ks + g0 * 8);
        glds16(base + (size_t)(q0 + r1) * QKVW + lc1 * 8, Ks + g1 * 8);
        __syncthreads();

        bf16x8 qf[2];
        {
            const int qrow = 16 * w + l15;
            qf[0] = *(const bf16x8*)(Ks + qrow * 64 + ((quad    ) ^ (qrow & 7)) * 8);
            qf[1] = *(const bf16x8*)(Ks + qrow * 64 + ((quad + 4) ^ (qrow & 7)) * 8);
        }

        f32x4 ot[4];
#pragma unroll
        for (int dt = 0; dt < 4; ++dt) ot[dt] = (f32x4){0.f, 0.f, 0.f, 0.f};
        float mrun = -1e30f, lsum = 0.f;

        for (int j0 = 0; j0 <= q0; j0 += 64) {
            __syncthreads();   // qf read / prev iter frag reads done
            glds16(base + (size_t)(j0 + r0) * QKVW + 768 + lc0 * 8, Ks + g0 * 8);
            glds16(base + (size_t)(j0 + r1) * QKVW + 768 + lc1 * 8, Ks + g1 * 8);
            {   // stage V^T: 4x4 register transpose
                const int k4 = (t & 15) * 4, d4 = (t >> 4) * 4;
                const unsigned short* vb = base + 1536 + d4;
                const ushort4 a0 = *(const ushort4*)(vb + (size_t)(j0 + k4 + 0) * QKVW);
                const ushort4 a1 = *(const ushort4*)(vb + (size_t)(j0 + k4 + 1) * QKVW);
                const ushort4 a2 = *(const ushort4*)(vb + (size_t)(j0 + k4 + 2) * QKVW);
                const ushort4 a3 = *(const ushort4*)(vb + (size_t)(j0 + k4 + 3) * QKVW);
                ushort4 c0, c1, c2, c3;
                c0.x = a0.x; c0.y = a1.x; c0.z = a2.x; c0.w = a3.x;
                c1.x = a0.y; c1.y = a1.y; c1.z = a2.y; c1.w = a3.y;
                c2.x = a0.z; c2.y = a1.z; c2.z = a2.z; c2.w = a3.z;
                c3.x = a0.w; c3.y = a1.w; c3.z = a2.w; c3.w = a3.w;
                *(ushort4*)(Vt + (size_t)(d4 + 0) * 72 + k4) = c0;
                *(ushort4*)(Vt + (size_t)(d4 + 1) * 72 + k4) = c1;
                *(ushort4*)(Vt + (size_t)(d4 + 2) * 72 + k4) = c2;
                *(ushort4*)(Vt + (size_t)(d4 + 3) * 72 + k4) = c3;
            }
            __syncthreads();

            // ---- S^T = K.Q^T ----
            f32x4 st[4];
#pragma unroll
            for (int mt = 0; mt < 4; ++mt) {
                st[mt] = (f32x4){0.f, 0.f, 0.f, 0.f};
                const int krow = 16 * mt + l15;
                const bf16x8 kf0 = *(const bf16x8*)(Ks + krow * 64 + ((quad    ) ^ (krow & 7)) * 8);
                const bf16x8 kf1 = *(const bf16x8*)(Ks + krow * 64 + ((quad + 4) ^ (krow & 7)) * 8);
                st[mt] = __builtin_amdgcn_mfma_f32_16x16x32_bf16(kf0, qf[0], st[mt], 0, 0, 0);
                st[mt] = __builtin_amdgcn_mfma_f32_16x16x32_bf16(kf1, qf[1], st[mt], 0, 0, 0);
            }

            // ---- causal mask (diagonal tile only) ----
            if (j0 == q0) {
                const int qin = 16 * w + l15;
#pragma unroll
                for (int mt = 0; mt < 4; ++mt)
#pragma unroll
                    for (int r = 0; r < 4; ++r)
                        if (16 * mt + 4 * quad + r > qin) st[mt][r] = -1e30f;
            }

            // ---- online softmax per query column ----
            float nm = st[0][0];
#pragma unroll
            for (int mt = 0; mt < 4; ++mt)
#pragma unroll
                for (int r = 0; r < 4; ++r) nm = fmaxf(nm, st[mt][r]);
            nm = fmaxf(nm, __shfl_xor(nm, 16, 64));
            nm = fmaxf(nm, __shfl_xor(nm, 32, 64));
            const float mnew = fmaxf(mrun, nm);
            const float alpha = __builtin_amdgcn_exp2f((mrun - mnew) * SM);
            float ps[4][4];
            float rs = 0.f;
#pragma unroll
            for (int mt = 0; mt < 4; ++mt)
#pragma unroll
                for (int r = 0; r < 4; ++r) {
                    const float p = __builtin_amdgcn_exp2f((st[mt][r] - mnew) * SM);
                    ps[mt][r] = p; rs += p;
                }
            rs += __shfl_xor(rs, 16, 64);
            rs += __shfl_xor(rs, 32, 64);
            lsum = lsum * alpha + rs;
            mrun = mnew;
#pragma unroll
            for (int dt = 0; dt < 4; ++dt) {
                ot[dt][0] *= alpha; ot[dt][1] *= alpha; ot[dt][2] *= alpha; ot[dt][3] *= alpha;
            }

            bf16x4 pf[4];
#pragma unroll
            for (int c = 0; c < 4; ++c) {
                bf16x4 p;
                p[0] = (short)f2bf(ps[c][0]);
                p[1] = (short)f2bf(ps[c][1]);
                p[2] = (short)f2bf(ps[c][2]);
                p[3] = (short)f2bf(ps[c][3]);
                pf[c] = p;
            }

            // ---- O^T += V^T . P^T ----
#pragma unroll
            for (int c = 0; c < 4; ++c)
#pragma unroll
                for (int dt = 0; dt < 4; ++dt) {
                    const bf16x4 vf = *(const bf16x4*)(Vt + (size_t)(16 * dt + l15) * 72 + 16 * c + 4 * quad);
                    ot[dt] = __builtin_amdgcn_mfma_f32_16x16x16bf16_1k(vf, pf[c], ot[dt], 0, 0, 0);
                }
        }

        // ---- epilogue: O^T/l -> Vt transpose -> coalesced bf16 stores ----
        __syncthreads();
        const float inv = 1.0f / lsum;
#pragma unroll
        for (int dt = 0; dt < 4; ++dt)
#pragma unroll
            for (int r = 0; r < 4; ++r)
                Vt[(16 * w + l15) * 72 + 16 * dt + 4 * quad + r] = f2bf(ot[dt][r] * inv);
        __syncthreads();
        {
            const int row = t & 63, hf = t >> 6;
            const u32x4 v0 = *(const u32x4*)(Vt + row * 72 + hf * 16);
            const u32x4 v1 = *(const u32x4*)(Vt + row * 72 + hf * 16 + 8);
            unsigned short* dst = attb + (size_t)(b * T + q0 + row) * H + h * 64 + hf * 16;
            *(u32x4*)dst = v0; *(u32x4*)(dst + 8) = v1;
        }
    }
}

extern "C" void kernel_launch(void* const* d_in, const int* in_sizes, int n_in,
                              void* d_out, int out_size, void* d_ws, size_t ws_size,
                              hipStream_t stream) {
    const float* x      = (const float*)d_in[0];
    const float* W_attn = (const float*)d_in[1];
    const float* b_attn = (const float*)d_in[2];
    const float* W_proj = (const float*)d_in[3];
    const float* b_proj = (const float*)d_in[4];
    float* out = (float*)d_out;

    const int Bn = 8, T = 1024, H = 768, NH = 12;
    const int M = Bn * T;            // 8192
    const int N1 = 3 * H;            // 2304

    unsigned short* xb   = (unsigned short*)d_ws;                 // M*H
    unsigned short* Wta  = xb + (size_t)M * H;                    // N1*H (n-major)
    unsigned short* Wtp  = Wta + (size_t)N1 * H;                  // H*H  (n-major)
    unsigned short* qkvb = Wtp + (size_t)H * H;                   // M*N1
    unsigned short* attb = qkvb + (size_t)M * N1;                 // M*H

    dim3 blk(256);

    cvt_f32_bf16<<<dim3((M * H) / 1024), blk, 0, stream>>>(x, xb);
    transpose_w<<<dim3(H / 64, N1 / 64), blk, 0, stream>>>(W_attn, Wta, H, N1);
    transpose_w<<<dim3(H / 64, H / 64), blk, 0, stream>>>(W_proj, Wtp, H, H);

    gemm_bf16<<<dim3(M / 128, N1 / 128), blk, 0, stream>>>(xb, Wta, b_attn, qkvb, M, N1, H, 1);

    attn_mfma<<<dim3(Bn * NH * 8), blk, 0, stream>>>(qkvb, attb);

    gemm_bf16<<<dim3(M / 128, H / 128), blk, 0, stream>>>(attb, Wtp, b_proj, out, M, H, H, 0);
}